// Round 15
// baseline (223.457 us; speedup 1.0000x reference)
//
#include <hip/hip_runtime.h>
#include <math.h>

// Problem constants
#define BQ 128
#define SQ 100
#define HH 16
#define LL 48
#define BS (BQ*SQ)        // 12800 rows

typedef __bf16 bf16_t;
typedef bf16_t bf16x8 __attribute__((ext_vector_type(8)));
typedef float f32x4 __attribute__((ext_vector_type(4)));

// Workspace byte offsets (peak ~197.3 MB)
#define QBH_OFF  0ull            // 26,214,400 q bf16 [bs][1024]
#define KBH_OFF  26214400ull     // 26,214,400 k bf16
#define VT_OFF   52428800ull     // 33,554,432 v^T bf16 [bh][64][128]
#define XB_OFF   85983232ull     // 26,214,400 x bf16 (dead after kgemm)
#define WB_OFF   112197632ull    // 6,291,456 Wcat bf16 (dead after kgemm)
#define WRFB_OFF 118489088ull    // 131,072 Wrf bf16
#define G_OFF    118620160ull    // 28,672 G bf16 [112][128]
#define SC_OFF   197292032ull    // 16 B scalars

__device__ __forceinline__ void gload16(const bf16_t* g, bf16_t* l) {
    __builtin_amdgcn_global_load_lds(
        (const __attribute__((address_space(1))) void*)g,
        (__attribute__((address_space(3))) void*)l, 16, 0, 0);
}

// ---------------- fused prologue: x/W/Wrf->bf16, G, vt-pad, sc-zero (one launch) -------
__global__ __launch_bounds__(256)
void kprep(const float* __restrict__ x, const float* __restrict__ Wq,
           const float* __restrict__ Wk, const float* __restrict__ Wv,
           const float* __restrict__ Wrf, const float* __restrict__ E,
           const float* __restrict__ F,
           bf16_t* __restrict__ xb, bf16_t* __restrict__ wb,
           bf16_t* __restrict__ wrfb, bf16_t* __restrict__ G,
           bf16_t* __restrict__ vt, float* __restrict__ sc) {
    const int bid = blockIdx.x;
    const int tid = threadIdx.x;
    if (bid < 1024) {
        const f32x4* x4 = (const f32x4*)x;
        for (int i = bid*256 + tid; i < BS*1024/4; i += 1024*256) {
            f32x4 v = x4[i];
            bf16_t* o = xb + 4*(size_t)i;
            o[0]=(bf16_t)v[0]; o[1]=(bf16_t)v[1]; o[2]=(bf16_t)v[2]; o[3]=(bf16_t)v[3];
        }
    } else if (bid < 1536) {
        for (int i = (bid-1024)*256 + tid; i < 3*1024*1024/4; i += 512*256) {
            const int f = i*4;
            const int row = f >> 10;
            const int col = f & 1023;
            const float* src = (row < 1024) ? Wq : ((row < 2048) ? Wk : Wv);
            const f32x4 v = *(const f32x4*)(src + ((size_t)(row & 1023) << 10) + col);
            bf16_t* o = wb + (size_t)f;
            o[0]=(bf16_t)v[0]; o[1]=(bf16_t)v[1]; o[2]=(bf16_t)v[2]; o[3]=(bf16_t)v[3];
        }
    } else if (bid < 1792) {
        for (int i = (bid-1536)*256 + tid; i < 131072*14; i += 256*256) {
            const int row = i / 14, dw = i - row*14;
            ((unsigned int*)((char*)vt + (size_t)row*256 + 200))[dw] = 0u;
        }
    } else if (bid < 1856) {
        const int i = (bid-1792)*256 + tid;
        const f32x4 v = ((const f32x4*)Wrf)[i];
        bf16_t* p = wrfb + 4*(size_t)i;
        p[0]=(bf16_t)v[0]; p[1]=(bf16_t)v[1]; p[2]=(bf16_t)v[2]; p[3]=(bf16_t)v[3];
    } else if (bid < 1912) {
        const int idx = (bid-1856)*256 + tid;
        const int s = idx >> 7, t = idx & 127;
        float acc = 0.f;
        if (s < 100 && t < 100) {
#pragma unroll
            for (int l = 0; l < LL; l++) acc += E[s*LL+l]*F[t*LL+l];
        }
        G[idx] = (bf16_t)acc;
    } else {
        if (tid < 4) sc[tid] = 0.f;
    }
}

// ---------------- fused QKV GEMM: asymmetric 3A/2B LDS pipeline (40KB -> 4 blocks/CU) --
// natural 2D grid (24,100); blocks x in [0,8): q; [8,16): k; [16,24): v
// A (x panels, L3-streamed): 3 buffers, staged 2 iters ahead.
// B (W panels, L2-resident): 2 buffers, staged 1 iter ahead.
// Race-free: every STAGE issued after the barrier that follows the target
// buffer's last reads. vmcnt(2) drains A(t),B(t); A(t+1) stays in flight.
__global__ __launch_bounds__(256)
void kgemm(const bf16_t* __restrict__ xb, const bf16_t* __restrict__ wb,
           const float* __restrict__ bq, const float* __restrict__ bk,
           const float* __restrict__ bv,
           bf16_t* __restrict__ qbh, bf16_t* __restrict__ kbh,
           bf16_t* __restrict__ vt, float* __restrict__ ssq) {
    __shared__ __align__(16) bf16_t smem[20480];   // 40 KiB: A[3][4096] | B[2][4096]; epilogue reuses [0,16384)
    bf16_t* sA = smem;            // A buf a at a*4096
    bf16_t* sB = smem + 12288;    // B buf b at 12288 + b*4096
    const int lane = threadIdx.x & 63;
    const int wid  = threadIdx.x >> 6;
    const int row0 = blockIdx.y * 128;
    const int col0 = blockIdx.x * 128;
    const int wr = (wid >> 1) * 64;
    const int wc = (wid & 1) * 64;
    const int ar = lane & 15;
    const int kg = lane >> 4;

    const int srow = lane >> 2;
    const int sslot = (lane & 3) ^ ((lane >> 3) & 3);
    const int scol = sslot * 8;
    const bf16_t* gA0 = xb + (size_t)(row0 + wid*16 + srow) * 1024 + scol;
    const bf16_t* gA1 = gA0 + (size_t)64 * 1024;
    const bf16_t* gB0 = wb + (size_t)(col0 + wid*16 + srow) * 1024 + scol;
    const bf16_t* gB1 = gB0 + (size_t)64 * 1024;
    const int lOffA0 = (wid*16) * 32;
    const int lOffA1 = (64 + wid*16) * 32;

    const int aslot = (kg ^ ((ar >> 1) & 3)) * 8;

    f32x4 acc[4][4];
#pragma unroll
    for (int m = 0; m < 4; m++)
#pragma unroll
        for (int n = 0; n < 4; n++)
            acc[m][n] = (f32x4){0.f, 0.f, 0.f, 0.f};

#define STAGE_A(buf, t) do { const int kk_ = (t)*32; \
        gload16(gA0 + kk_, sA + (buf)*4096 + lOffA0); \
        gload16(gA1 + kk_, sA + (buf)*4096 + lOffA1); } while(0)
#define STAGE_B(buf, t) do { const int kk_ = (t)*32; \
        gload16(gB0 + kk_, sB + (buf)*4096 + lOffA0); \
        gload16(gB1 + kk_, sB + (buf)*4096 + lOffA1); } while(0)

    // prologue: order matters for vmcnt(2) at iter 0: {A(0),B(0)} oldest
    STAGE_A(0, 0);
    STAGE_B(0, 0);
    STAGE_A(1, 1);

    for (int ks = 0; ks < 32; ks++) {
        // drain A(ks),B(ks); A(ks+1) may stay in flight
        if (ks < 31) asm volatile("s_waitcnt vmcnt(2)" ::: "memory");
        else         asm volatile("s_waitcnt vmcnt(0)" ::: "memory");
        __builtin_amdgcn_sched_barrier(0);
        __builtin_amdgcn_s_barrier();
        __builtin_amdgcn_sched_barrier(0);
        if (ks + 1 < 32) STAGE_B((ks + 1) & 1, ks + 1);
        if (ks + 2 < 32) STAGE_A((ks + 2) % 3, ks + 2);
        const int pa = (ks % 3) * 4096;
        const int pb = (ks & 1) * 4096;
        bf16x8 a[4], bb[4];
#pragma unroll
        for (int rf = 0; rf < 4; rf++)
            a[rf] = *(const bf16x8*)&sA[pa + (wr + rf*16 + ar)*32 + aslot];
#pragma unroll
        for (int cf = 0; cf < 4; cf++)
            bb[cf] = *(const bf16x8*)&sB[pb + (wc + cf*16 + ar)*32 + aslot];
#pragma unroll
        for (int rf = 0; rf < 4; rf++)
#pragma unroll
            for (int cf = 0; cf < 4; cf++)
                acc[rf][cf] = __builtin_amdgcn_mfma_f32_16x16x32_bf16(
                    a[rf], bb[cf], acc[rf][cf], 0, 0, 0);
    }
#undef STAGE_A
#undef STAGE_B

    const int which = col0 >> 10;
    const int cc0 = col0 & 1023;

    __syncthreads();   // all K-loop LDS reads done; epilogue reuses smem[0,16384)

    float ss = 0.f;
    if (which < 2) {
#pragma unroll
        for (int n = 0; n < 4; n++) {
            const float bias = (which == 0 ? bq : bk)[cc0 + wc + n*16 + ar];
            const int c = wc + n*16 + ar;
#pragma unroll
            for (int m = 0; m < 4; m++) {
#pragma unroll
                for (int j = 0; j < 4; j++) {
                    const int r = wr + m*16 + kg*4 + j;
                    const float val = acc[m][n][j] + bias;
                    ss += val * val;
                    smem[r*128 + (c ^ ((r&7)<<3))] = (bf16_t)val;
                }
            }
        }
    } else {
#pragma unroll
        for (int n = 0; n < 4; n++) {
            const float bias = bv[cc0 + wc + n*16 + ar];
            const int c = wc + n*16 + ar;
#pragma unroll
            for (int m = 0; m < 4; m++) {
#pragma unroll
                for (int j = 0; j < 4; j++) {
                    const int r = wr + m*16 + kg*4 + j;
                    const float val = acc[m][n][j] + bias;
                    smem[c*128 + (r ^ ((c&7)<<3))] = (bf16_t)val;
                }
            }
        }
    }
    __syncthreads();

    if (which < 2) {
        bf16_t* ob = (which == 0) ? qbh : kbh;
#pragma unroll
        for (int i = 0; i < 8; i++) {
            const int e = i*2048 + threadIdx.x*8;
            const int r = e >> 7;
            const int c0 = e & 127;
            const bf16x8 chunk = *(const bf16x8*)&smem[r*128 + (c0 ^ ((r&7)<<3))];
            *(bf16x8*)(ob + (size_t)(row0 + r)*1024 + cc0 + c0) = chunk;
        }
        for (int off = 32; off; off >>= 1) ss += __shfl_xor(ss, off);
        if (lane == 0 && ss != 0.f) atomicAdd(ssq + which, ss);
    } else {
#pragma unroll
        for (int i = 0; i < 8; i++) {
            const int e = i*2048 + threadIdx.x*8;
            const int c = e >> 7;
            const int r0 = e & 127;
            const bf16x8 chunk = *(const bf16x8*)&smem[c*128 + (r0 ^ ((c&7)<<3))];
            const int cc = cc0 + c;
            const int h2 = cc >> 6, d = cc & 63;
            const int rg = row0 + r0;
            const int b2 = rg / 100;
            const int s2 = rg - b2*100;
            if (s2 <= 92) {
                *(bf16x8*)(vt + ((size_t)(b2*16 + h2)*64 + d)*128 + s2) = chunk;
            } else {
#pragma unroll
                for (int t = 0; t < 8; t++) {
                    const int rgt = rg + t;
                    const int b3 = rgt / 100;
                    const int s3 = rgt - b3*100;
                    vt[((size_t)(b3*16 + h2)*64 + d)*128 + s3] = chunk[t];
                }
            }
        }
    }
}

// ---------------- fused phi + Wt + P + numerator: one block per (b,h) ------------------
__global__ __launch_bounds__(256)
void kfused(const bf16_t* __restrict__ qbh, const bf16_t* __restrict__ kbh,
            const bf16_t* __restrict__ wrfb, const float* __restrict__ sc,
            const bf16_t* __restrict__ vt, const bf16_t* __restrict__ G,
            float* __restrict__ out) {
    __shared__ __align__(16) char pool[60928];
    bf16_t* tQ = (bf16_t*)pool;              // [112][72] = 16128 B
    bf16_t* tK = (bf16_t*)(pool + 16128);    // [112][72] = 16128 B
    bf16_t* sP = (bf16_t*)(pool + 32256);    // [112][128] swizzled = 28672 B
    bf16_t* sW = (bf16_t*)pool;              // [64][128] swizzled = 16384 B (overlay)

    const int lane = threadIdx.x & 63;
    const int w    = threadIdx.x >> 6;
    const int bh   = blockIdx.x;
    const int b = bh >> 4, h = bh & 15;
    const int ar = lane & 15;
    const int kg = lane >> 4;

    // ---- phase 1+2: proj + phi -> tQ/tK ----
    {
        bf16x8 bfr[4][2];
#pragma unroll
        for (int cf = 0; cf < 4; cf++)
#pragma unroll
            for (int ks = 0; ks < 2; ks++)
                bfr[cf][ks] = *(const bf16x8*)(wrfb +
                    ((size_t)(h * 64 + cf * 16 + ar) * 64 + ks * 32 + kg * 8));

        const float qs  = rsqrtf(sc[0]);
        const float ksc = rsqrtf(sc[1]);
        const float CPHI = 0.009477041545882225f;  // exp(-0.5)/64

#pragma unroll
        for (int rr = 0; rr < 2; rr++) {
            const int rf = w + rr*4;
            if (rf > 6) continue;
            int s_src = rf*16 + ar; s_src = s_src > 99 ? 99 : s_src;
            const size_t urow = ((size_t)(b*100 + s_src) * 16 + h) * 64 + kg * 8;
            const bf16x8 a0 = *(const bf16x8*)(qbh + urow);
            const bf16x8 a1 = *(const bf16x8*)(qbh + urow + 32);
            const bf16x8 c0 = *(const bf16x8*)(kbh + urow);
            const bf16x8 c1 = *(const bf16x8*)(kbh + urow + 32);
            f32x4 aq[4], ak[4];
#pragma unroll
            for (int cf = 0; cf < 4; cf++) {
                aq[cf] = (f32x4){0.f,0.f,0.f,0.f};
                ak[cf] = (f32x4){0.f,0.f,0.f,0.f};
            }
#pragma unroll
            for (int cf = 0; cf < 4; cf++) {
                aq[cf] = __builtin_amdgcn_mfma_f32_16x16x32_bf16(a0, bfr[cf][0], aq[cf], 0, 0, 0);
                aq[cf] = __builtin_amdgcn_mfma_f32_16x16x32_bf16(a1, bfr[cf][1], aq[cf], 0, 0, 0);
                ak[cf] = __builtin_amdgcn_mfma_f32_16x16x32_bf16(c0, bfr[cf][0], ak[cf], 0, 0, 0);
                ak[cf] = __builtin_amdgcn_mfma_f32_16x16x32_bf16(c1, bfr[cf][1], ak[cf], 0, 0, 0);
            }
            float t[4] = {0.f,0.f,0.f,0.f};
            float vq[4][4], vk[4][4];
#pragma unroll
            for (int cf = 0; cf < 4; cf++) {
#pragma unroll
                for (int j = 0; j < 4; j++) {
                    const float q_ = expf(aq[cf][j] * qs) * CPHI;
                    const float k_ = expf(ak[cf][j] * ksc) * CPHI;
                    vq[cf][j] = q_;
                    vk[cf][j] = k_;
                    t[j] += q_ * k_;
                }
            }
#pragma unroll
            for (int j = 0; j < 4; j++) {
                t[j] += __shfl_xor(t[j], 1);
                t[j] += __shfl_xor(t[j], 2);
                t[j] += __shfl_xor(t[j], 4);
                t[j] += __shfl_xor(t[j], 8);
                t[j] = 1.0f / t[j];
            }
#pragma unroll
            for (int cf = 0; cf < 4; cf++) {
#pragma unroll
                for (int j = 0; j < 4; j++) {
                    const int rr2 = rf*16 + kg*4 + j;
                    tQ[rr2*72 + cf*16 + ar] = (bf16_t)(vq[cf][j] * t[j]);  // phi_q / den
                    tK[rr2*72 + cf*16 + ar] = (bf16_t)vk[cf][j];
                }
            }
        }
    }
    __syncthreads();

    // ---- phase 3: P -> sP ----
    {
        bf16x8 bfr[7][2];
#pragma unroll
        for (int cf = 0; cf < 7; cf++) {
            const int sp = cf*16 + ar;
#pragma unroll
            for (int ks = 0; ks < 2; ks++)
                bfr[cf][ks] = *(const bf16x8*)&tK[sp*72 + ks*32 + kg*8];
        }
#pragma unroll
        for (int rr = 0; rr < 2; rr++) {
            const int rf = w + rr*4;
            if (rf > 6) continue;
            const int s = rf*16 + ar;
            const bf16x8 a0 = *(const bf16x8*)&tQ[s*72 + kg*8];
            const bf16x8 a1 = *(const bf16x8*)&tQ[s*72 + 32 + kg*8];
            f32x4 acc[7];
#pragma unroll
            for (int cf = 0; cf < 7; cf++) acc[cf] = (f32x4){0.f,0.f,0.f,0.f};
#pragma unroll
            for (int cf = 0; cf < 7; cf++) {
                acc[cf] = __builtin_amdgcn_mfma_f32_16x16x32_bf16(a0, bfr[cf][0], acc[cf], 0, 0, 0);
                acc[cf] = __builtin_amdgcn_mfma_f32_16x16x32_bf16(a1, bfr[cf][1], acc[cf], 0, 0, 0);
            }
#pragma unroll
            for (int cf = 0; cf < 7; cf++) {
#pragma unroll
                for (int j = 0; j < 4; j++) {
                    const int so = rf*16 + kg*4 + j;
                    const int sp = cf*16 + ar;
                    if (so < 100)
                        sP[so*128 + (sp ^ ((so&7)<<3))] =
                            (bf16_t)(sp < 100 ? acc[cf][j] : 0.f);
                }
            }
#pragma unroll
            for (int j = 0; j < 4; j++) {
                const int so = rf*16 + kg*4 + j;
                if (so < 100) {
                    const int sp = 112 + ar;
                    sP[so*128 + (sp ^ ((so&7)<<3))] = (bf16_t)0.f;
                }
            }
        }
    }
    __syncthreads();

    // ---- phase 4: Wt -> sW (overlays dead tQ/tK) ----
    {
        const bf16_t* vb = vt + (size_t)bh * 8192;
        bf16x8 a[4];
#pragma unroll
        for (int ks = 0; ks < 4; ks++)
            a[ks] = *(const bf16x8*)(vb + (w*16 + ar)*128 + ks*32 + kg*8);

#pragma unroll
        for (int cf = 0; cf < 7; cf++) {
            f32x4 acc = (f32x4){0.f,0.f,0.f,0.f};
#pragma unroll
            for (int ks = 0; ks < 4; ks++) {
                const bf16x8 bb = *(const bf16x8*)(G + (cf*16 + ar)*128 + ks*32 + kg*8);
                acc = __builtin_amdgcn_mfma_f32_16x16x32_bf16(a[ks], bb, acc, 0, 0, 0);
            }
#pragma unroll
            for (int j = 0; j < 4; j++) {
                const int d = w*16 + kg*4 + j;
                const int sp = cf*16 + ar;
                sW[d*128 + (sp ^ ((d&7)<<3))] = (bf16_t)acc[j];
            }
        }
#pragma unroll
        for (int j = 0; j < 4; j++) {
            const int d = w*16 + kg*4 + j;
            sW[d*128 + ((112 + ar) ^ ((d&7)<<3))] = (bf16_t)0.f;
        }
    }
    __syncthreads();

    // ---- phase 5: out = P * Wt^T ----
    {
        bf16x8 wfr[4][4];
#pragma unroll
        for (int cf = 0; cf < 4; cf++) {
            const int d = cf*16 + ar;
#pragma unroll
            for (int ks = 0; ks < 4; ks++)
                wfr[cf][ks] = *(const bf16x8*)&sW[d*128 + ((ks*32 + kg*8) ^ ((d&7)<<3))];
        }
#pragma unroll
        for (int rr = 0; rr < 2; rr++) {
            const int rf = w + rr*4;
            if (rf > 6) continue;
            int s = rf*16 + ar; s = s > 99 ? 99 : s;
            bf16x8 a[4];
#pragma unroll
            for (int ks = 0; ks < 4; ks++)
                a[ks] = *(const bf16x8*)&sP[s*128 + ((ks*32 + kg*8) ^ ((s&7)<<3))];
            f32x4 acc[4];
#pragma unroll
            for (int cf = 0; cf < 4; cf++) acc[cf] = (f32x4){0.f,0.f,0.f,0.f};
#pragma unroll
            for (int cf = 0; cf < 4; cf++)
#pragma unroll
                for (int ks = 0; ks < 4; ks++)
                    acc[cf] = __builtin_amdgcn_mfma_f32_16x16x32_bf16(a[ks], wfr[cf][ks], acc[cf], 0, 0, 0);
#pragma unroll
            for (int cf = 0; cf < 4; cf++) {
#pragma unroll
                for (int j = 0; j < 4; j++) {
                    const int so = rf*16 + kg*4 + j;
                    if (so < 100)
                        out[((size_t)(b*100 + so)*16 + h)*64 + cf*16 + ar] = acc[cf][j];
                }
            }
        }
    }
}

extern "C" void kernel_launch(void* const* d_in, const int* in_sizes, int n_in,
                              void* d_out, int out_size, void* d_ws, size_t ws_size,
                              hipStream_t stream) {
    const float* x   = (const float*)d_in[0];
    const float* Wq  = (const float*)d_in[1];
    const float* bq  = (const float*)d_in[2];
    const float* Wk  = (const float*)d_in[3];
    const float* bk  = (const float*)d_in[4];
    const float* Wv  = (const float*)d_in[5];
    const float* bv  = (const float*)d_in[6];
    const float* Wrf = (const float*)d_in[7];
    const float* E   = (const float*)d_in[8];
    const float* F   = (const float*)d_in[9];
    float* out = (float*)d_out;

    char* ws = (char*)d_ws;
    bf16_t* qbh  = (bf16_t*)(ws + QBH_OFF);
    bf16_t* kbh  = (bf16_t*)(ws + KBH_OFF);
    bf16_t* vt   = (bf16_t*)(ws + VT_OFF);
    bf16_t* xb   = (bf16_t*)(ws + XB_OFF);
    bf16_t* wb   = (bf16_t*)(ws + WB_OFF);
    bf16_t* wrfb = (bf16_t*)(ws + WRFB_OFF);
    bf16_t* G    = (bf16_t*)(ws + G_OFF);
    float*  sc   = (float*)(ws + SC_OFF);

    kprep<<<1913, 256, 0, stream>>>(x, Wq, Wk, Wv, Wrf, E, F,
                                    xb, wb, wrfb, G, vt, sc);

    dim3 ggrid(24, 100);   // 3072/128 cols x 12800/128 rows
    kgemm<<<ggrid, 256, 0, stream>>>(xb, wb, bq, bk, bv, qbh, kbh, vt, sc);

    kfused<<<BQ * HH, 256, 0, stream>>>(qbh, kbh, wrfb, sc, vt, G, out);
}

// Round 16
// 211.301 us; speedup vs baseline: 1.0575x; 1.0575x over previous
//
#include <hip/hip_runtime.h>
#include <math.h>

// Problem constants
#define BQ 128
#define SQ 100
#define HH 16
#define LL 48
#define BS (BQ*SQ)        // 12800 rows

typedef __bf16 bf16_t;
typedef bf16_t bf16x8 __attribute__((ext_vector_type(8)));
typedef float f32x4 __attribute__((ext_vector_type(4)));

// Workspace byte offsets (peak ~197.3 MB)
#define QBH_OFF  0ull            // 26,214,400 q bf16 [bs][1024]
#define KBH_OFF  26214400ull     // 26,214,400 k bf16
#define VT_OFF   52428800ull     // 33,554,432 v^T bf16 [bh][64][128]
#define XB_OFF   85983232ull     // 26,214,400 x bf16 (dead after kgemm)
#define WB_OFF   112197632ull    // 6,291,456 Wcat bf16 (dead after kgemm)
#define WRFB_OFF 118489088ull    // 131,072 Wrf bf16
#define G_OFF    118620160ull    // 28,672 G bf16 [112][128]
#define SC_OFF   197292032ull    // 16 B scalars

__device__ __forceinline__ void gload16(const bf16_t* g, bf16_t* l) {
    __builtin_amdgcn_global_load_lds(
        (const __attribute__((address_space(1))) void*)g,
        (__attribute__((address_space(3))) void*)l, 16, 0, 0);
}

// ---------------- fused prologue: x/W/Wrf->bf16, G, vt-pad, sc-zero (one launch) -------
__global__ __launch_bounds__(256)
void kprep(const float* __restrict__ x, const float* __restrict__ Wq,
           const float* __restrict__ Wk, const float* __restrict__ Wv,
           const float* __restrict__ Wrf, const float* __restrict__ E,
           const float* __restrict__ F,
           bf16_t* __restrict__ xb, bf16_t* __restrict__ wb,
           bf16_t* __restrict__ wrfb, bf16_t* __restrict__ G,
           bf16_t* __restrict__ vt, float* __restrict__ sc) {
    const int bid = blockIdx.x;
    const int tid = threadIdx.x;
    if (bid < 1024) {
        const f32x4* x4 = (const f32x4*)x;
        for (int i = bid*256 + tid; i < BS*1024/4; i += 1024*256) {
            f32x4 v = x4[i];
            bf16_t* o = xb + 4*(size_t)i;
            o[0]=(bf16_t)v[0]; o[1]=(bf16_t)v[1]; o[2]=(bf16_t)v[2]; o[3]=(bf16_t)v[3];
        }
    } else if (bid < 1536) {
        for (int i = (bid-1024)*256 + tid; i < 3*1024*1024/4; i += 512*256) {
            const int f = i*4;
            const int row = f >> 10;
            const int col = f & 1023;
            const float* src = (row < 1024) ? Wq : ((row < 2048) ? Wk : Wv);
            const f32x4 v = *(const f32x4*)(src + ((size_t)(row & 1023) << 10) + col);
            bf16_t* o = wb + (size_t)f;
            o[0]=(bf16_t)v[0]; o[1]=(bf16_t)v[1]; o[2]=(bf16_t)v[2]; o[3]=(bf16_t)v[3];
        }
    } else if (bid < 1792) {
        for (int i = (bid-1536)*256 + tid; i < 131072*14; i += 256*256) {
            const int row = i / 14, dw = i - row*14;
            ((unsigned int*)((char*)vt + (size_t)row*256 + 200))[dw] = 0u;
        }
    } else if (bid < 1856) {
        const int i = (bid-1792)*256 + tid;
        const f32x4 v = ((const f32x4*)Wrf)[i];
        bf16_t* p = wrfb + 4*(size_t)i;
        p[0]=(bf16_t)v[0]; p[1]=(bf16_t)v[1]; p[2]=(bf16_t)v[2]; p[3]=(bf16_t)v[3];
    } else if (bid < 1912) {
        const int idx = (bid-1856)*256 + tid;
        const int s = idx >> 7, t = idx & 127;
        float acc = 0.f;
        if (s < 100 && t < 100) {
#pragma unroll
            for (int l = 0; l < LL; l++) acc += E[s*LL+l]*F[t*LL+l];
        }
        G[idx] = (bf16_t)acc;
    } else {
        if (tid < 4) sc[tid] = 0.f;
    }
}

// ---------------- fused QKV GEMM: 3-deep pipeline + vectorized LDS epilogue ----------
// natural 2D grid (24,100); blocks x in [0,8): q; [8,16): k; [16,24): v
__global__ __launch_bounds__(256)
void kgemm(const bf16_t* __restrict__ xb, const bf16_t* __restrict__ wb,
           const float* __restrict__ bq, const float* __restrict__ bk,
           const float* __restrict__ bv,
           bf16_t* __restrict__ qbh, bf16_t* __restrict__ kbh,
           bf16_t* __restrict__ vt, float* __restrict__ ssq) {
    __shared__ __align__(16) bf16_t smem[24576];   // 48 KiB: 3xA | 3xB; epilogue reuses [0,16384)
    bf16_t* sA = smem;
    bf16_t* sB = smem + 12288;
    const int lane = threadIdx.x & 63;
    const int wid  = threadIdx.x >> 6;
    const int row0 = blockIdx.y * 128;
    const int col0 = blockIdx.x * 128;
    const int wr = (wid >> 1) * 64;
    const int wc = (wid & 1) * 64;
    const int ar = lane & 15;
    const int kg = lane >> 4;

    const int srow = lane >> 2;
    const int sslot = (lane & 3) ^ ((lane >> 3) & 3);
    const int scol = sslot * 8;
    const bf16_t* gA0 = xb + (size_t)(row0 + wid*16 + srow) * 1024 + scol;
    const bf16_t* gA1 = gA0 + (size_t)64 * 1024;
    const bf16_t* gB0 = wb + (size_t)(col0 + wid*16 + srow) * 1024 + scol;
    const bf16_t* gB1 = gB0 + (size_t)64 * 1024;
    const int lOffA0 = (wid*16) * 32;
    const int lOffA1 = (64 + wid*16) * 32;

    const int aslot = (kg ^ ((ar >> 1) & 3)) * 8;

    f32x4 acc[4][4];
#pragma unroll
    for (int m = 0; m < 4; m++)
#pragma unroll
        for (int n = 0; n < 4; n++)
            acc[m][n] = (f32x4){0.f, 0.f, 0.f, 0.f};

#define STAGE(buf, t) do { const int kk_ = (t)*32; \
        gload16(gA0 + kk_, sA + (buf)*4096 + lOffA0); \
        gload16(gA1 + kk_, sA + (buf)*4096 + lOffA1); \
        gload16(gB0 + kk_, sB + (buf)*4096 + lOffA0); \
        gload16(gB1 + kk_, sB + (buf)*4096 + lOffA1); } while(0)

    STAGE(0, 0);
    STAGE(1, 1);

    for (int ks = 0; ks < 32; ks++) {
        if (ks < 31) asm volatile("s_waitcnt vmcnt(4)" ::: "memory");
        else         asm volatile("s_waitcnt vmcnt(0)" ::: "memory");
        __builtin_amdgcn_sched_barrier(0);
        __builtin_amdgcn_s_barrier();
        __builtin_amdgcn_sched_barrier(0);
        const int p = ks % 3;
        if (ks + 2 < 32) {
            const int nb = (ks + 2) % 3;
            STAGE(nb, ks + 2);
        }
        bf16x8 a[4], bb[4];
#pragma unroll
        for (int rf = 0; rf < 4; rf++)
            a[rf] = *(const bf16x8*)&sA[p*4096 + (wr + rf*16 + ar)*32 + aslot];
#pragma unroll
        for (int cf = 0; cf < 4; cf++)
            bb[cf] = *(const bf16x8*)&sB[p*4096 + (wc + cf*16 + ar)*32 + aslot];
#pragma unroll
        for (int rf = 0; rf < 4; rf++)
#pragma unroll
            for (int cf = 0; cf < 4; cf++)
                acc[rf][cf] = __builtin_amdgcn_mfma_f32_16x16x32_bf16(
                    a[rf], bb[cf], acc[rf][cf], 0, 0, 0);
    }
#undef STAGE

    const int which = col0 >> 10;
    const int cc0 = col0 & 1023;

    __syncthreads();

    float ss = 0.f;
    if (which < 2) {
#pragma unroll
        for (int n = 0; n < 4; n++) {
            const float bias = (which == 0 ? bq : bk)[cc0 + wc + n*16 + ar];
            const int c = wc + n*16 + ar;
#pragma unroll
            for (int m = 0; m < 4; m++) {
#pragma unroll
                for (int j = 0; j < 4; j++) {
                    const int r = wr + m*16 + kg*4 + j;
                    const float val = acc[m][n][j] + bias;
                    ss += val * val;
                    smem[r*128 + (c ^ ((r&7)<<3))] = (bf16_t)val;
                }
            }
        }
    } else {
#pragma unroll
        for (int n = 0; n < 4; n++) {
            const float bias = bv[cc0 + wc + n*16 + ar];
            const int c = wc + n*16 + ar;
#pragma unroll
            for (int m = 0; m < 4; m++) {
#pragma unroll
                for (int j = 0; j < 4; j++) {
                    const int r = wr + m*16 + kg*4 + j;
                    const float val = acc[m][n][j] + bias;
                    smem[c*128 + (r ^ ((c&7)<<3))] = (bf16_t)val;
                }
            }
        }
    }
    __syncthreads();

    if (which < 2) {
        bf16_t* ob = (which == 0) ? qbh : kbh;
#pragma unroll
        for (int i = 0; i < 8; i++) {
            const int e = i*2048 + threadIdx.x*8;
            const int r = e >> 7;
            const int c0 = e & 127;
            const bf16x8 chunk = *(const bf16x8*)&smem[r*128 + (c0 ^ ((r&7)<<3))];
            *(bf16x8*)(ob + (size_t)(row0 + r)*1024 + cc0 + c0) = chunk;
        }
        for (int off = 32; off; off >>= 1) ss += __shfl_xor(ss, off);
        if (lane == 0 && ss != 0.f) atomicAdd(ssq + which, ss);
    } else {
#pragma unroll
        for (int i = 0; i < 8; i++) {
            const int e = i*2048 + threadIdx.x*8;
            const int c = e >> 7;
            const int r0 = e & 127;
            const bf16x8 chunk = *(const bf16x8*)&smem[c*128 + (r0 ^ ((c&7)<<3))];
            const int cc = cc0 + c;
            const int h2 = cc >> 6, d = cc & 63;
            const int rg = row0 + r0;
            const int b2 = rg / 100;
            const int s2 = rg - b2*100;
            if (s2 <= 92) {
                *(bf16x8*)(vt + ((size_t)(b2*16 + h2)*64 + d)*128 + s2) = chunk;
            } else {
#pragma unroll
                for (int t = 0; t < 8; t++) {
                    const int rgt = rg + t;
                    const int b3 = rgt / 100;
                    const int s3 = rgt - b3*100;
                    vt[((size_t)(b3*16 + h2)*64 + d)*128 + s3] = chunk[t];
                }
            }
        }
    }
}

// ---------------- fused phi + Wt + P + numerator: one block per (b,h) ------------------
__global__ __launch_bounds__(256)
void kfused(const bf16_t* __restrict__ qbh, const bf16_t* __restrict__ kbh,
            const bf16_t* __restrict__ wrfb, const float* __restrict__ sc,
            const bf16_t* __restrict__ vt, const bf16_t* __restrict__ G,
            float* __restrict__ out) {
    __shared__ __align__(16) char pool[60928];
    bf16_t* tQ = (bf16_t*)pool;              // [112][72] = 16128 B
    bf16_t* tK = (bf16_t*)(pool + 16128);    // [112][72] = 16128 B
    bf16_t* sP = (bf16_t*)(pool + 32256);    // [112][128] swizzled = 28672 B
    bf16_t* sW = (bf16_t*)pool;              // [64][128] swizzled = 16384 B (overlay)

    const int lane = threadIdx.x & 63;
    const int w    = threadIdx.x >> 6;
    const int bh   = blockIdx.x;
    const int b = bh >> 4, h = bh & 15;
    const int ar = lane & 15;
    const int kg = lane >> 4;

    // ---- phase 1+2: proj + phi -> tQ/tK ----
    {
        bf16x8 bfr[4][2];
#pragma unroll
        for (int cf = 0; cf < 4; cf++)
#pragma unroll
            for (int ks = 0; ks < 2; ks++)
                bfr[cf][ks] = *(const bf16x8*)(wrfb +
                    ((size_t)(h * 64 + cf * 16 + ar) * 64 + ks * 32 + kg * 8));

        const float qs  = rsqrtf(sc[0]);
        const float ksc = rsqrtf(sc[1]);
        const float CPHI = 0.009477041545882225f;  // exp(-0.5)/64

#pragma unroll
        for (int rr = 0; rr < 2; rr++) {
            const int rf = w + rr*4;
            if (rf > 6) continue;
            int s_src = rf*16 + ar; s_src = s_src > 99 ? 99 : s_src;
            const size_t urow = ((size_t)(b*100 + s_src) * 16 + h) * 64 + kg * 8;
            const bf16x8 a0 = *(const bf16x8*)(qbh + urow);
            const bf16x8 a1 = *(const bf16x8*)(qbh + urow + 32);
            const bf16x8 c0 = *(const bf16x8*)(kbh + urow);
            const bf16x8 c1 = *(const bf16x8*)(kbh + urow + 32);
            f32x4 aq[4], ak[4];
#pragma unroll
            for (int cf = 0; cf < 4; cf++) {
                aq[cf] = (f32x4){0.f,0.f,0.f,0.f};
                ak[cf] = (f32x4){0.f,0.f,0.f,0.f};
            }
#pragma unroll
            for (int cf = 0; cf < 4; cf++) {
                aq[cf] = __builtin_amdgcn_mfma_f32_16x16x32_bf16(a0, bfr[cf][0], aq[cf], 0, 0, 0);
                aq[cf] = __builtin_amdgcn_mfma_f32_16x16x32_bf16(a1, bfr[cf][1], aq[cf], 0, 0, 0);
                ak[cf] = __builtin_amdgcn_mfma_f32_16x16x32_bf16(c0, bfr[cf][0], ak[cf], 0, 0, 0);
                ak[cf] = __builtin_amdgcn_mfma_f32_16x16x32_bf16(c1, bfr[cf][1], ak[cf], 0, 0, 0);
            }
            float t[4] = {0.f,0.f,0.f,0.f};
            float vq[4][4], vk[4][4];
#pragma unroll
            for (int cf = 0; cf < 4; cf++) {
#pragma unroll
                for (int j = 0; j < 4; j++) {
                    const float q_ = expf(aq[cf][j] * qs) * CPHI;
                    const float k_ = expf(ak[cf][j] * ksc) * CPHI;
                    vq[cf][j] = q_;
                    vk[cf][j] = k_;
                    t[j] += q_ * k_;
                }
            }
#pragma unroll
            for (int j = 0; j < 4; j++) {
                t[j] += __shfl_xor(t[j], 1);
                t[j] += __shfl_xor(t[j], 2);
                t[j] += __shfl_xor(t[j], 4);
                t[j] += __shfl_xor(t[j], 8);
                t[j] = 1.0f / t[j];
            }
#pragma unroll
            for (int cf = 0; cf < 4; cf++) {
#pragma unroll
                for (int j = 0; j < 4; j++) {
                    const int rr2 = rf*16 + kg*4 + j;
                    tQ[rr2*72 + cf*16 + ar] = (bf16_t)(vq[cf][j] * t[j]);  // phi_q / den
                    tK[rr2*72 + cf*16 + ar] = (bf16_t)vk[cf][j];
                }
            }
        }
    }
    __syncthreads();

    // ---- phase 3: P -> sP ----
    {
        bf16x8 bfr[7][2];
#pragma unroll
        for (int cf = 0; cf < 7; cf++) {
            const int sp = cf*16 + ar;
#pragma unroll
            for (int ks = 0; ks < 2; ks++)
                bfr[cf][ks] = *(const bf16x8*)&tK[sp*72 + ks*32 + kg*8];
        }
#pragma unroll
        for (int rr = 0; rr < 2; rr++) {
            const int rf = w + rr*4;
            if (rf > 6) continue;
            const int s = rf*16 + ar;
            const bf16x8 a0 = *(const bf16x8*)&tQ[s*72 + kg*8];
            const bf16x8 a1 = *(const bf16x8*)&tQ[s*72 + 32 + kg*8];
            f32x4 acc[7];
#pragma unroll
            for (int cf = 0; cf < 7; cf++) acc[cf] = (f32x4){0.f,0.f,0.f,0.f};
#pragma unroll
            for (int cf = 0; cf < 7; cf++) {
                acc[cf] = __builtin_amdgcn_mfma_f32_16x16x32_bf16(a0, bfr[cf][0], acc[cf], 0, 0, 0);
                acc[cf] = __builtin_amdgcn_mfma_f32_16x16x32_bf16(a1, bfr[cf][1], acc[cf], 0, 0, 0);
            }
#pragma unroll
            for (int cf = 0; cf < 7; cf++) {
#pragma unroll
                for (int j = 0; j < 4; j++) {
                    const int so = rf*16 + kg*4 + j;
                    const int sp = cf*16 + ar;
                    if (so < 100)
                        sP[so*128 + (sp ^ ((so&7)<<3))] =
                            (bf16_t)(sp < 100 ? acc[cf][j] : 0.f);
                }
            }
#pragma unroll
            for (int j = 0; j < 4; j++) {
                const int so = rf*16 + kg*4 + j;
                if (so < 100) {
                    const int sp = 112 + ar;
                    sP[so*128 + (sp ^ ((so&7)<<3))] = (bf16_t)0.f;
                }
            }
        }
    }
    __syncthreads();

    // ---- phase 4: Wt -> sW (overlays dead tQ/tK) ----
    {
        const bf16_t* vb = vt + (size_t)bh * 8192;
        bf16x8 a[4];
#pragma unroll
        for (int ks = 0; ks < 4; ks++)
            a[ks] = *(const bf16x8*)(vb + (w*16 + ar)*128 + ks*32 + kg*8);

#pragma unroll
        for (int cf = 0; cf < 7; cf++) {
            f32x4 acc = (f32x4){0.f,0.f,0.f,0.f};
#pragma unroll
            for (int ks = 0; ks < 4; ks++) {
                const bf16x8 bb = *(const bf16x8*)(G + (cf*16 + ar)*128 + ks*32 + kg*8);
                acc = __builtin_amdgcn_mfma_f32_16x16x32_bf16(a[ks], bb, acc, 0, 0, 0);
            }
#pragma unroll
            for (int j = 0; j < 4; j++) {
                const int d = w*16 + kg*4 + j;
                const int sp = cf*16 + ar;
                sW[d*128 + (sp ^ ((d&7)<<3))] = (bf16_t)acc[j];
            }
        }
#pragma unroll
        for (int j = 0; j < 4; j++) {
            const int d = w*16 + kg*4 + j;
            sW[d*128 + ((112 + ar) ^ ((d&7)<<3))] = (bf16_t)0.f;
        }
    }
    __syncthreads();

    // ---- phase 5: out = P * Wt^T ----
    {
        bf16x8 wfr[4][4];
#pragma unroll
        for (int cf = 0; cf < 4; cf++) {
            const int d = cf*16 + ar;
#pragma unroll
            for (int ks = 0; ks < 4; ks++)
                wfr[cf][ks] = *(const bf16x8*)&sW[d*128 + ((ks*32 + kg*8) ^ ((d&7)<<3))];
        }
#pragma unroll
        for (int rr = 0; rr < 2; rr++) {
            const int rf = w + rr*4;
            if (rf > 6) continue;
            int s = rf*16 + ar; s = s > 99 ? 99 : s;
            bf16x8 a[4];
#pragma unroll
            for (int ks = 0; ks < 4; ks++)
                a[ks] = *(const bf16x8*)&sP[s*128 + ((ks*32 + kg*8) ^ ((s&7)<<3))];
            f32x4 acc[4];
#pragma unroll
            for (int cf = 0; cf < 4; cf++) acc[cf] = (f32x4){0.f,0.f,0.f,0.f};
#pragma unroll
            for (int cf = 0; cf < 4; cf++)
#pragma unroll
                for (int ks = 0; ks < 4; ks++)
                    acc[cf] = __builtin_amdgcn_mfma_f32_16x16x32_bf16(a[ks], wfr[cf][ks], acc[cf], 0, 0, 0);
#pragma unroll
            for (int cf = 0; cf < 4; cf++) {
#pragma unroll
                for (int j = 0; j < 4; j++) {
                    const int so = rf*16 + kg*4 + j;
                    if (so < 100)
                        out[((size_t)(b*100 + so)*16 + h)*64 + cf*16 + ar] = acc[cf][j];
                }
            }
        }
    }
}

extern "C" void kernel_launch(void* const* d_in, const int* in_sizes, int n_in,
                              void* d_out, int out_size, void* d_ws, size_t ws_size,
                              hipStream_t stream) {
    const float* x   = (const float*)d_in[0];
    const float* Wq  = (const float*)d_in[1];
    const float* bq  = (const float*)d_in[2];
    const float* Wk  = (const float*)d_in[3];
    const float* bk  = (const float*)d_in[4];
    const float* Wv  = (const float*)d_in[5];
    const float* bv  = (const float*)d_in[6];
    const float* Wrf = (const float*)d_in[7];
    const float* E   = (const float*)d_in[8];
    const float* F   = (const float*)d_in[9];
    float* out = (float*)d_out;

    char* ws = (char*)d_ws;
    bf16_t* qbh  = (bf16_t*)(ws + QBH_OFF);
    bf16_t* kbh  = (bf16_t*)(ws + KBH_OFF);
    bf16_t* vt   = (bf16_t*)(ws + VT_OFF);
    bf16_t* xb   = (bf16_t*)(ws + XB_OFF);
    bf16_t* wb   = (bf16_t*)(ws + WB_OFF);
    bf16_t* wrfb = (bf16_t*)(ws + WRFB_OFF);
    bf16_t* G    = (bf16_t*)(ws + G_OFF);
    float*  sc   = (float*)(ws + SC_OFF);

    kprep<<<1913, 256, 0, stream>>>(x, Wq, Wk, Wv, Wrf, E, F,
                                    xb, wb, wrfb, G, vt, sc);

    dim3 ggrid(24, 100);   // 3072/128 cols x 12800/128 rows
    kgemm<<<ggrid, 256, 0, stream>>>(xb, wb, bq, bk, bv, qbh, kbh, vt, sc);

    kfused<<<BQ * HH, 256, 0, stream>>>(qbh, kbh, wrfb, sc, vt, G, out);
}